// Round 1
// baseline (923.265 us; speedup 1.0000x reference)
//
#include <hip/hip_runtime.h>

#define N_NODES 100000
#define N_EDGES 3200000
#define N_GRAPHS 512

// ---------- degree histogram over dst ----------
__global__ void k_deg(const int* __restrict__ ei, int* __restrict__ deg) {
    int e = blockIdx.x * 256 + threadIdx.x;
    if (e < N_EDGES) atomicAdd(&deg[ei[N_EDGES + e]], 1);
}

// ---------- exclusive scan of deg -> row_ptr (3-kernel scan), plus dinv ----------
__global__ void k_scan1(const int* __restrict__ deg, int* __restrict__ rp,
                        int* __restrict__ bsums, float* __restrict__ dinv) {
    __shared__ int sd[256];
    int t = threadIdx.x;
    int base = blockIdx.x * 1024 + t * 4;
    int v[4];
#pragma unroll
    for (int j = 0; j < 4; j++) {
        v[j] = (base + j < N_NODES) ? deg[base + j] : 0;
        if (base + j < N_NODES) dinv[base + j] = rsqrtf((float)v[j] + 1.0f);
    }
    int s = v[0] + v[1] + v[2] + v[3];
    sd[t] = s; __syncthreads();
    for (int off = 1; off < 256; off <<= 1) {
        int x = (t >= off) ? sd[t - off] : 0;
        __syncthreads();
        sd[t] += x;
        __syncthreads();
    }
    if (t == 255) bsums[blockIdx.x] = sd[255];
    int excl = sd[t] - s;
#pragma unroll
    for (int j = 0; j < 4; j++) {
        if (base + j < N_NODES) rp[base + j] = excl;
        excl += v[j];
    }
}

__global__ void k_scan2(int* __restrict__ bsums, int nb) {
    __shared__ int sd[128];
    int t = threadIdx.x;
    int v = (t < nb) ? bsums[t] : 0;
    sd[t] = v; __syncthreads();
    for (int off = 1; off < 128; off <<= 1) {
        int x = (t >= off) ? sd[t - off] : 0;
        __syncthreads();
        sd[t] += x;
        __syncthreads();
    }
    if (t < nb) bsums[t] = sd[t] - v;
}

__global__ void k_scan3(int* __restrict__ rp, const int* __restrict__ bsums,
                        int* __restrict__ cursor, const int* __restrict__ batch,
                        int* __restrict__ cnt) {
    int i = blockIdx.x * 256 + threadIdx.x;
    if (i < N_NODES) {
        int v = rp[i] + bsums[i >> 10];
        rp[i] = v;
        cursor[i] = v;
        atomicAdd(&cnt[batch[i]], 1);   // graph-size histogram (batch is int)
    }
    if (i == 0) rp[N_NODES] = N_EDGES;
}

// ---------- CSR fill: csr[rp[dst]..] = src ----------
__global__ void k_fill(const int* __restrict__ ei, int* __restrict__ cursor,
                       int* __restrict__ csr) {
    int e = blockIdx.x * 256 + threadIdx.x;
    if (e < N_EDGES) {
        int dst = ei[N_EDGES + e];
        int pos = atomicAdd(&cursor[dst], 1);
        csr[pos] = ei[e];
    }
}

// ---------- H1 = x @ W1  ([100000,128] @ [128,32]) ----------
__global__ void k_gemm1(const float* __restrict__ x, const float* __restrict__ W1,
                        float* __restrict__ H1) {
    __shared__ float Ws[128 * 32];   // 16 KB
    __shared__ float xs[32 * 128];   // 16 KB (32 rows)
    int t = threadIdx.x;
    const float4* W4 = (const float4*)W1;
    float4* Ws4 = (float4*)Ws;
#pragma unroll
    for (int i = 0; i < 4; i++) Ws4[t + 256 * i] = W4[t + 256 * i];
    int row0 = blockIdx.x * 32;                 // N divisible by 32 (3125 blocks)
    const float4* x4 = (const float4*)(x + (size_t)row0 * 128);
    float4* xs4 = (float4*)xs;
#pragma unroll
    for (int i = 0; i < 4; i++) xs4[t + 256 * i] = x4[t + 256 * i];
    __syncthreads();
    int col = t & 31;
    int rb = (t >> 5) * 4;
    float a0 = 0.f, a1 = 0.f, a2 = 0.f, a3 = 0.f;
#pragma unroll 8
    for (int k = 0; k < 128; k++) {
        float w = Ws[k * 32 + col];
        a0 += xs[(rb + 0) * 128 + k] * w;
        a1 += xs[(rb + 1) * 128 + k] * w;
        a2 += xs[(rb + 2) * 128 + k] * w;
        a3 += xs[(rb + 3) * 128 + k] * w;
    }
    float* o = H1 + (size_t)(row0 + rb) * 32 + col;
    o[0] = a0; o[32] = a1; o[64] = a2; o[96] = a3;
}

// ---------- H2 = h1 @ W2  ([100000,32] @ [32,32]) ----------
__global__ void k_gemm2(const float* __restrict__ h1, const float* __restrict__ W2,
                        float* __restrict__ H2) {
    __shared__ float Ws[32 * 32];  // 4 KB
    __shared__ float xs[32 * 32];  // 4 KB
    int t = threadIdx.x;
    ((float4*)Ws)[t] = ((const float4*)W2)[t];
    int row0 = blockIdx.x * 32;
    ((float4*)xs)[t] = ((const float4*)(h1 + (size_t)row0 * 32))[t];
    __syncthreads();
    int col = t & 31;
    int rb = (t >> 5) * 4;
    float a0 = 0.f, a1 = 0.f, a2 = 0.f, a3 = 0.f;
#pragma unroll
    for (int k = 0; k < 32; k++) {
        float w = Ws[k * 32 + col];
        a0 += xs[(rb + 0) * 32 + k] * w;
        a1 += xs[(rb + 1) * 32 + k] * w;
        a2 += xs[(rb + 2) * 32 + k] * w;
        a3 += xs[(rb + 3) * 32 + k] * w;
    }
    float* o = H2 + (size_t)(row0 + rb) * 32 + col;
    o[0] = a0; o[32] = a1; o[64] = a2; o[96] = a3;
}

// ---------- layer-1 aggregation: one wave per dst node ----------
// h1[dst][f] = relu( (sum_e H[src_e][f]*dinv[src_e]) * dinv[dst]
//                    + H[dst][f]*dinv[dst]^2 + b[f] )
__global__ void k_gather1(const float* __restrict__ H, const float* __restrict__ dinv,
                          const int* __restrict__ rp, const int* __restrict__ csr,
                          const float* __restrict__ bias, float* __restrict__ hout) {
    int wid = (blockIdx.x * 256 + threadIdx.x) >> 6;
    if (wid >= N_NODES) return;
    int lane = threadIdx.x & 63;
    int f = lane & 31, half = lane >> 5;
    int beg = rp[wid], end = rp[wid + 1];
    float acc = 0.f;
    for (int e = beg + half; e < end; e += 2) {
        int s = csr[e];
        acc += H[(size_t)s * 32 + f] * dinv[s];
    }
    acc += __shfl_xor(acc, 32);
    if (half == 0) {
        float di = dinv[wid];
        float v = acc * di + H[(size_t)wid * 32 + f] * di * di + bias[f];
        hout[(size_t)wid * 32 + f] = fmaxf(v, 0.f);
    }
}

// ---------- layer-2 aggregation fused with mean-pool numerator ----------
__global__ void k_gather2(const float* __restrict__ H, const float* __restrict__ dinv,
                          const int* __restrict__ rp, const int* __restrict__ csr,
                          const float* __restrict__ bias, const int* __restrict__ batch,
                          float* __restrict__ pool) {
    int wid = (blockIdx.x * 256 + threadIdx.x) >> 6;
    if (wid >= N_NODES) return;
    int lane = threadIdx.x & 63;
    int f = lane & 31, half = lane >> 5;
    int beg = rp[wid], end = rp[wid + 1];
    float acc = 0.f;
    for (int e = beg + half; e < end; e += 2) {
        int s = csr[e];
        acc += H[(size_t)s * 32 + f] * dinv[s];
    }
    acc += __shfl_xor(acc, 32);
    if (half == 0) {
        float di = dinv[wid];
        float v = acc * di + H[(size_t)wid * 32 + f] * di * di + bias[f];
        v = fmaxf(v, 0.f);
        atomicAdd(&pool[(size_t)batch[wid] * 32 + f], v);
    }
}

// ---------- head: out[g] = (pool[g]/cnt[g]) @ Wl + bl ----------
__global__ void k_final(const float* __restrict__ pool, const int* __restrict__ cnt,
                        const float* __restrict__ Wl, const float* __restrict__ bl,
                        float* __restrict__ out) {
    int g = blockIdx.x * 256 + threadIdx.x;
    if (g >= N_GRAPHS) return;
    float inv = 1.0f / fmaxf((float)cnt[g], 1.0f);
    float a0 = bl[0], a1 = bl[1];
#pragma unroll
    for (int f = 0; f < 32; f++) {
        float p = pool[g * 32 + f] * inv;
        a0 += p * Wl[f * 2 + 0];
        a1 += p * Wl[f * 2 + 1];
    }
    out[g * 2 + 0] = a0;
    out[g * 2 + 1] = a1;
}

extern "C" void kernel_launch(void* const* d_in, const int* in_sizes, int n_in,
                              void* d_out, int out_size, void* d_ws, size_t ws_size,
                              hipStream_t stream) {
    const float* x    = (const float*)d_in[0];
    const int*   ei   = (const int*)d_in[1];   // [2, E] row-major: src then dst
    const int*   batch= (const int*)d_in[2];
    const float* W1   = (const float*)d_in[3];
    const float* b1   = (const float*)d_in[4];
    const float* W2   = (const float*)d_in[5];
    const float* b2   = (const float*)d_in[6];
    const float* Wl   = (const float*)d_in[7];
    const float* bl   = (const float*)d_in[8];
    float* out = (float*)d_out;

    char* w = (char*)d_ws;
    size_t off = 0;
    auto take = [&](size_t bytes) -> char* {
        char* p = w + off;
        off = (off + bytes + 255) & ~(size_t)255;
        return p;
    };
    float* H1   = (float*)take((size_t)N_NODES * 32 * 4);
    float* h1   = (float*)take((size_t)N_NODES * 32 * 4);
    float* H2   = (float*)take((size_t)N_NODES * 32 * 4);
    int*   csr  = (int*)  take((size_t)N_EDGES * 4);
    float* dinv = (float*)take((size_t)N_NODES * 4);
    int*   degc = (int*)  take((size_t)N_NODES * 4);   // histogram, then cursor
    int*   rp   = (int*)  take((size_t)(N_NODES + 1) * 4);
    int*   bsum = (int*)  take(4096);
    float* pool = (float*)take((size_t)N_GRAPHS * 32 * 4);
    int*   cnt  = (int*)  take((size_t)N_GRAPHS * 4);

    hipMemsetAsync(degc, 0, (size_t)N_NODES * 4, stream);
    hipMemsetAsync(pool, 0, (size_t)N_GRAPHS * 32 * 4, stream);
    hipMemsetAsync(cnt, 0, (size_t)N_GRAPHS * 4, stream);

    const int nscan = (N_NODES + 1023) / 1024;  // 98
    k_deg  <<<N_EDGES / 256, 256, 0, stream>>>(ei, degc);
    k_scan1<<<nscan, 256, 0, stream>>>(degc, rp, bsum, dinv);
    k_scan2<<<1, 128, 0, stream>>>(bsum, nscan);
    k_scan3<<<(N_NODES + 255) / 256, 256, 0, stream>>>(rp, bsum, degc, batch, cnt);
    k_fill <<<N_EDGES / 256, 256, 0, stream>>>(ei, degc, csr);
    k_gemm1<<<N_NODES / 32, 256, 0, stream>>>(x, W1, H1);
    k_gather1<<<N_NODES / 4, 256, 0, stream>>>(H1, dinv, rp, csr, b1, h1);
    k_gemm2<<<N_NODES / 32, 256, 0, stream>>>(h1, W2, H2);
    k_gather2<<<N_NODES / 4, 256, 0, stream>>>(H2, dinv, rp, csr, b2, batch, pool);
    k_final<<<2, 256, 0, stream>>>(pool, cnt, Wl, bl, out);
}

// Round 2
// 617.085 us; speedup vs baseline: 1.4962x; 1.4962x over previous
//
#include <hip/hip_runtime.h>

#define N_NODES 100000
#define N_EDGES 3200000
#define N_GRAPHS 512
#define NB 391                 // dst buckets of 256 nodes: (100000+255)/256
#define FILL_CHUNK 16384
#define FILL_BLOCKS ((N_EDGES + FILL_CHUNK - 1) / FILL_CHUNK)   // 196

// ---------- pass 1: global bucket histogram (bucket = dst >> 8) ----------
__global__ void k_hist(const int* __restrict__ ei, int* __restrict__ gtot) {
    __shared__ int h[NB];
    int t = threadIdx.x;
    for (int i = t; i < NB; i += 256) h[i] = 0;
    __syncthreads();
    int stride = gridDim.x * 256;
    for (int e = blockIdx.x * 256 + t; e < N_EDGES; e += stride)
        atomicAdd(&h[ei[N_EDGES + e] >> 8], 1);
    __syncthreads();
    for (int i = t; i < NB; i += 256) if (h[i]) atomicAdd(&gtot[i], h[i]);
}

// ---------- pass 2: exclusive scan of bucket totals ----------
__global__ void k_bscan(const int* __restrict__ gtot, int* __restrict__ base,
                        int* __restrict__ cursor) {
    __shared__ int sd[512];
    int t = threadIdx.x;
    int v = (t < NB) ? gtot[t] : 0;
    sd[t] = v; __syncthreads();
    for (int off = 1; off < 512; off <<= 1) {
        int x = (t >= off) ? sd[t - off] : 0;
        __syncthreads(); sd[t] += x; __syncthreads();
    }
    int excl = sd[t] - v;
    if (t < NB) { base[t] = excl; cursor[t] = excl; }
    if (t == NB - 1) base[NB] = excl + v;   // == N_EDGES
}

// ---------- pass 3: bin edges into buckets, packed (dstlocal<<17 | src) ----------
__global__ void k_binfill(const int* __restrict__ ei, int* __restrict__ gcur,
                          unsigned* __restrict__ packed) {
    __shared__ int h[NB];
    __shared__ int base[NB];
    int t = threadIdx.x;
    for (int i = t; i < NB; i += 256) h[i] = 0;
    __syncthreads();
    int s0 = blockIdx.x * FILL_CHUNK;
    int s1 = min(s0 + FILL_CHUNK, N_EDGES);
    for (int e = s0 + t; e < s1; e += 256)
        atomicAdd(&h[ei[N_EDGES + e] >> 8], 1);
    __syncthreads();
    for (int i = t; i < NB; i += 256) {
        int c = h[i];
        base[i] = c ? atomicAdd(&gcur[i], c) : 0;
        h[i] = 0;
    }
    __syncthreads();
    for (int e = s0 + t; e < s1; e += 256) {
        int dst = ei[N_EDGES + e];
        int bk = dst >> 8;
        int pos = base[bk] + atomicAdd(&h[bk], 1);
        packed[pos] = (unsigned)ei[e] | (((unsigned)dst & 255u) << 17);
    }
}

// ---------- pass 4: per-bucket deg/rp/dinv/cnt + exact CSR fill ----------
__global__ void k_csr(const unsigned* __restrict__ packed, const int* __restrict__ base,
                      const int* __restrict__ batch,
                      int* __restrict__ rp, float* __restrict__ dinv,
                      int* __restrict__ csr, int* __restrict__ cnt) {
    __shared__ int deg[256];
    __shared__ int sd[256];
    __shared__ int cur[256];
    int t = threadIdx.x;
    int b = blockIdx.x;
    deg[t] = 0;
    __syncthreads();
    int bb = base[b], be = base[b + 1];
    for (int e = bb + t; e < be; e += 256)
        atomicAdd(&deg[packed[e] >> 17], 1);
    __syncthreads();
    int d = deg[t];
    sd[t] = d; __syncthreads();
    for (int off = 1; off < 256; off <<= 1) {
        int x = (t >= off) ? sd[t - off] : 0;
        __syncthreads(); sd[t] += x; __syncthreads();
    }
    int pos0 = bb + sd[t] - d;               // exclusive scan within bucket
    cur[t] = pos0;
    int node = b * 256 + t;
    if (node < N_NODES) {
        rp[node] = pos0;
        dinv[node] = rsqrtf((float)d + 1.0f);
        atomicAdd(&cnt[batch[node]], 1);
    }
    if (node == N_NODES - 1) rp[N_NODES] = N_EDGES;
    __syncthreads();
    for (int e = bb + t; e < be; e += 256) {
        unsigned p = packed[e];
        int pos = atomicAdd(&cur[p >> 17], 1);
        csr[pos] = (int)(p & 0x1FFFFu);
    }
}

// ---------- H1 = x @ W1  ([100000,128] @ [128,32]) ----------
__global__ void k_gemm1(const float* __restrict__ x, const float* __restrict__ W1,
                        float* __restrict__ H1) {
    __shared__ float Ws[128 * 32];
    __shared__ float xs[32 * 128];
    int t = threadIdx.x;
    const float4* W4 = (const float4*)W1;
    float4* Ws4 = (float4*)Ws;
#pragma unroll
    for (int i = 0; i < 4; i++) Ws4[t + 256 * i] = W4[t + 256 * i];
    int row0 = blockIdx.x * 32;
    const float4* x4 = (const float4*)(x + (size_t)row0 * 128);
    float4* xs4 = (float4*)xs;
#pragma unroll
    for (int i = 0; i < 4; i++) xs4[t + 256 * i] = x4[t + 256 * i];
    __syncthreads();
    int col = t & 31;
    int rb = (t >> 5) * 4;
    float a0 = 0.f, a1 = 0.f, a2 = 0.f, a3 = 0.f;
#pragma unroll 8
    for (int k = 0; k < 128; k++) {
        float w = Ws[k * 32 + col];
        a0 += xs[(rb + 0) * 128 + k] * w;
        a1 += xs[(rb + 1) * 128 + k] * w;
        a2 += xs[(rb + 2) * 128 + k] * w;
        a3 += xs[(rb + 3) * 128 + k] * w;
    }
    float* o = H1 + (size_t)(row0 + rb) * 32 + col;
    o[0] = a0; o[32] = a1; o[64] = a2; o[96] = a3;
}

// ---------- H2 = h1 @ W2  ([100000,32] @ [32,32]) ----------
__global__ void k_gemm2(const float* __restrict__ h1, const float* __restrict__ W2,
                        float* __restrict__ H2) {
    __shared__ float Ws[32 * 32];
    __shared__ float xs[32 * 32];
    int t = threadIdx.x;
    ((float4*)Ws)[t] = ((const float4*)W2)[t];
    int row0 = blockIdx.x * 32;
    ((float4*)xs)[t] = ((const float4*)(h1 + (size_t)row0 * 32))[t];
    __syncthreads();
    int col = t & 31;
    int rb = (t >> 5) * 4;
    float a0 = 0.f, a1 = 0.f, a2 = 0.f, a3 = 0.f;
#pragma unroll
    for (int k = 0; k < 32; k++) {
        float w = Ws[k * 32 + col];
        a0 += xs[(rb + 0) * 32 + k] * w;
        a1 += xs[(rb + 1) * 32 + k] * w;
        a2 += xs[(rb + 2) * 32 + k] * w;
        a3 += xs[(rb + 3) * 32 + k] * w;
    }
    float* o = H2 + (size_t)(row0 + rb) * 32 + col;
    o[0] = a0; o[32] = a1; o[64] = a2; o[96] = a3;
}

// ---------- layer-1 aggregation: one wave per dst node ----------
__global__ void k_gather1(const float* __restrict__ H, const float* __restrict__ dinv,
                          const int* __restrict__ rp, const int* __restrict__ csr,
                          const float* __restrict__ bias, float* __restrict__ hout) {
    int wid = (blockIdx.x * 256 + threadIdx.x) >> 6;
    if (wid >= N_NODES) return;
    int lane = threadIdx.x & 63;
    int f = lane & 31, half = lane >> 5;
    int beg = rp[wid], end = rp[wid + 1];
    float acc = 0.f;
    for (int e = beg + half; e < end; e += 2) {
        int s = csr[e];
        acc += H[(size_t)s * 32 + f] * dinv[s];
    }
    acc += __shfl_xor(acc, 32);
    if (half == 0) {
        float di = dinv[wid];
        float v = acc * di + H[(size_t)wid * 32 + f] * di * di + bias[f];
        hout[(size_t)wid * 32 + f] = fmaxf(v, 0.f);
    }
}

// ---------- layer-2 aggregation fused with mean-pool numerator ----------
__global__ void k_gather2(const float* __restrict__ H, const float* __restrict__ dinv,
                          const int* __restrict__ rp, const int* __restrict__ csr,
                          const float* __restrict__ bias, const int* __restrict__ batch,
                          float* __restrict__ pool) {
    int wid = (blockIdx.x * 256 + threadIdx.x) >> 6;
    if (wid >= N_NODES) return;
    int lane = threadIdx.x & 63;
    int f = lane & 31, half = lane >> 5;
    int beg = rp[wid], end = rp[wid + 1];
    float acc = 0.f;
    for (int e = beg + half; e < end; e += 2) {
        int s = csr[e];
        acc += H[(size_t)s * 32 + f] * dinv[s];
    }
    acc += __shfl_xor(acc, 32);
    if (half == 0) {
        float di = dinv[wid];
        float v = acc * di + H[(size_t)wid * 32 + f] * di * di + bias[f];
        v = fmaxf(v, 0.f);
        atomicAdd(&pool[(size_t)batch[wid] * 32 + f], v);
    }
}

// ---------- head ----------
__global__ void k_final(const float* __restrict__ pool, const int* __restrict__ cnt,
                        const float* __restrict__ Wl, const float* __restrict__ bl,
                        float* __restrict__ out) {
    int g = blockIdx.x * 256 + threadIdx.x;
    if (g >= N_GRAPHS) return;
    float inv = 1.0f / fmaxf((float)cnt[g], 1.0f);
    float a0 = bl[0], a1 = bl[1];
#pragma unroll
    for (int f = 0; f < 32; f++) {
        float p = pool[g * 32 + f] * inv;
        a0 += p * Wl[f * 2 + 0];
        a1 += p * Wl[f * 2 + 1];
    }
    out[g * 2 + 0] = a0;
    out[g * 2 + 1] = a1;
}

extern "C" void kernel_launch(void* const* d_in, const int* in_sizes, int n_in,
                              void* d_out, int out_size, void* d_ws, size_t ws_size,
                              hipStream_t stream) {
    const float* x    = (const float*)d_in[0];
    const int*   ei   = (const int*)d_in[1];
    const int*   batch= (const int*)d_in[2];
    const float* W1   = (const float*)d_in[3];
    const float* b1   = (const float*)d_in[4];
    const float* W2   = (const float*)d_in[5];
    const float* b2   = (const float*)d_in[6];
    const float* Wl   = (const float*)d_in[7];
    const float* bl   = (const float*)d_in[8];
    float* out = (float*)d_out;

    char* w = (char*)d_ws;
    size_t off = 0;
    auto take = [&](size_t bytes) -> char* {
        char* p = w + off;
        off = (off + bytes + 255) & ~(size_t)255;
        return p;
    };
    float*    H1     = (float*)take((size_t)N_NODES * 32 * 4);
    float*    h1     = (float*)take((size_t)N_NODES * 32 * 4);
    // packed (E*4B) and H2 (N*32*4B) are both 12.8 MB and have disjoint
    // lifetimes (packed dies at k_csr; H2 born at k_gemm2) -> alias them.
    char*     shared = take((size_t)N_EDGES * 4);
    unsigned* packed = (unsigned*)shared;
    float*    H2     = (float*)shared;
    int*      csr    = (int*)  take((size_t)N_EDGES * 4);
    float*    dinv   = (float*)take((size_t)N_NODES * 4);
    int*      rp     = (int*)  take((size_t)(N_NODES + 1) * 4);
    int*      gtot   = (int*)  take((size_t)(NB + 1) * 4);
    int*      base   = (int*)  take((size_t)(NB + 1) * 4);
    int*      gcur   = (int*)  take((size_t)(NB + 1) * 4);
    float*    pool   = (float*)take((size_t)N_GRAPHS * 32 * 4);
    int*      cnt    = (int*)  take((size_t)N_GRAPHS * 4);

    hipMemsetAsync(gtot, 0, (size_t)(NB + 1) * 4, stream);
    hipMemsetAsync(pool, 0, (size_t)N_GRAPHS * 32 * 4, stream);
    hipMemsetAsync(cnt, 0, (size_t)N_GRAPHS * 4, stream);

    k_hist   <<<512, 256, 0, stream>>>(ei, gtot);
    k_bscan  <<<1, 512, 0, stream>>>(gtot, base, gcur);
    k_binfill<<<FILL_BLOCKS, 256, 0, stream>>>(ei, gcur, packed);
    k_csr    <<<NB, 256, 0, stream>>>(packed, base, batch, rp, dinv, csr, cnt);
    k_gemm1  <<<N_NODES / 32, 256, 0, stream>>>(x, W1, H1);
    k_gather1<<<N_NODES / 4, 256, 0, stream>>>(H1, dinv, rp, csr, b1, h1);
    k_gemm2  <<<N_NODES / 32, 256, 0, stream>>>(h1, W2, H2);
    k_gather2<<<N_NODES / 4, 256, 0, stream>>>(H2, dinv, rp, csr, b2, batch, pool);
    k_final  <<<2, 256, 0, stream>>>(pool, cnt, Wl, bl, out);
}

// Round 3
// 481.316 us; speedup vs baseline: 1.9182x; 1.2821x over previous
//
#include <hip/hip_runtime.h>

#define N_NODES 100000
#define N_EDGES 3200000
#define N_GRAPHS 512
#define NB 391                 // dst buckets of 256 nodes
#define FILL_CHUNK 16384
#define FILL_BLOCKS ((N_EDGES + FILL_CHUNK - 1) / FILL_CHUNK)   // 196

// ---------- pass 1: global bucket histogram (bucket = dst >> 8) ----------
__global__ void k_hist(const int* __restrict__ ei, int* __restrict__ gtot) {
    __shared__ int h[NB];
    int t = threadIdx.x;
    for (int i = t; i < NB; i += 256) h[i] = 0;
    __syncthreads();
    int stride = gridDim.x * 256;
    for (int e = blockIdx.x * 256 + t; e < N_EDGES; e += stride)
        atomicAdd(&h[ei[N_EDGES + e] >> 8], 1);
    __syncthreads();
    for (int i = t; i < NB; i += 256) if (h[i]) atomicAdd(&gtot[i], h[i]);
}

// ---------- pass 2: exclusive scan of bucket totals ----------
__global__ void k_bscan(const int* __restrict__ gtot, int* __restrict__ base,
                        int* __restrict__ cursor) {
    __shared__ int sd[512];
    int t = threadIdx.x;
    int v = (t < NB) ? gtot[t] : 0;
    sd[t] = v; __syncthreads();
    for (int off = 1; off < 512; off <<= 1) {
        int x = (t >= off) ? sd[t - off] : 0;
        __syncthreads(); sd[t] += x; __syncthreads();
    }
    int excl = sd[t] - v;
    if (t < NB) { base[t] = excl; cursor[t] = excl; }
    if (t == NB - 1) base[NB] = excl + v;   // == N_EDGES
}

// ---------- pass 3: bin edges into buckets, packed (dstlocal<<17 | src) ----------
__global__ void k_binfill(const int* __restrict__ ei, int* __restrict__ gcur,
                          unsigned* __restrict__ packed) {
    __shared__ int h[NB];
    __shared__ int base[NB];
    int t = threadIdx.x;
    for (int i = t; i < NB; i += 256) h[i] = 0;
    __syncthreads();
    int s0 = blockIdx.x * FILL_CHUNK;
    int s1 = min(s0 + FILL_CHUNK, N_EDGES);
    for (int e = s0 + t; e < s1; e += 256)
        atomicAdd(&h[ei[N_EDGES + e] >> 8], 1);
    __syncthreads();
    for (int i = t; i < NB; i += 256) {
        int c = h[i];
        base[i] = c ? atomicAdd(&gcur[i], c) : 0;
        h[i] = 0;
    }
    __syncthreads();
    for (int e = s0 + t; e < s1; e += 256) {
        int dst = ei[N_EDGES + e];
        int bk = dst >> 8;
        int pos = base[bk] + atomicAdd(&h[bk], 1);
        packed[pos] = (unsigned)ei[e] | (((unsigned)dst & 255u) << 17);
    }
}

// ---------- pass 4: per-bucket deg/rp/dinv/cnt + exact CSR fill ----------
__global__ void k_csr(const unsigned* __restrict__ packed, const int* __restrict__ base,
                      const int* __restrict__ batch,
                      int* __restrict__ rp, float* __restrict__ dinv,
                      int* __restrict__ csr, int* __restrict__ cnt) {
    __shared__ int deg[256];
    __shared__ int sd[256];
    __shared__ int cur[256];
    int t = threadIdx.x;
    int b = blockIdx.x;
    deg[t] = 0;
    __syncthreads();
    int bb = base[b], be = base[b + 1];
    for (int e = bb + t; e < be; e += 256)
        atomicAdd(&deg[packed[e] >> 17], 1);
    __syncthreads();
    int d = deg[t];
    sd[t] = d; __syncthreads();
    for (int off = 1; off < 256; off <<= 1) {
        int x = (t >= off) ? sd[t - off] : 0;
        __syncthreads(); sd[t] += x; __syncthreads();
    }
    int pos0 = bb + sd[t] - d;
    cur[t] = pos0;
    int node = b * 256 + t;
    if (node < N_NODES) {
        rp[node] = pos0;
        dinv[node] = rsqrtf((float)d + 1.0f);
        atomicAdd(&cnt[batch[node]], 1);
    }
    if (node == N_NODES - 1) rp[N_NODES] = N_EDGES;
    __syncthreads();
    for (int e = bb + t; e < be; e += 256) {
        unsigned p = packed[e];
        int pos = atomicAdd(&cur[p >> 17], 1);
        csr[pos] = (int)(p & 0x1FFFFu);
    }
}

// ---------- H1s = (x @ W1) * dinv[row]  ([100000,128] @ [128,32]) ----------
__global__ void k_gemm1(const float* __restrict__ x, const float* __restrict__ W1,
                        const float* __restrict__ dinv, float* __restrict__ H1s) {
    __shared__ float Ws[128 * 32];
    __shared__ float xs[32 * 128];
    int t = threadIdx.x;
    const float4* W4 = (const float4*)W1;
    float4* Ws4 = (float4*)Ws;
#pragma unroll
    for (int i = 0; i < 4; i++) Ws4[t + 256 * i] = W4[t + 256 * i];
    int row0 = blockIdx.x * 32;
    const float4* x4 = (const float4*)(x + (size_t)row0 * 128);
    float4* xs4 = (float4*)xs;
#pragma unroll
    for (int i = 0; i < 4; i++) xs4[t + 256 * i] = x4[t + 256 * i];
    __syncthreads();
    int col = t & 31;
    int rb = (t >> 5) * 4;
    float a0 = 0.f, a1 = 0.f, a2 = 0.f, a3 = 0.f;
#pragma unroll 8
    for (int k = 0; k < 128; k++) {
        float w = Ws[k * 32 + col];
        a0 += xs[(rb + 0) * 128 + k] * w;
        a1 += xs[(rb + 1) * 128 + k] * w;
        a2 += xs[(rb + 2) * 128 + k] * w;
        a3 += xs[(rb + 3) * 128 + k] * w;
    }
    int r = row0 + rb;
    float* o = H1s + (size_t)r * 32 + col;
    o[0]  = a0 * dinv[r + 0];
    o[32] = a1 * dinv[r + 1];
    o[64] = a2 * dinv[r + 2];
    o[96] = a3 * dinv[r + 3];
}

// ---------- H2s = (h1 @ W2) * dinv[row]  ([100000,32] @ [32,32]) ----------
__global__ void k_gemm2(const float* __restrict__ h1, const float* __restrict__ W2,
                        const float* __restrict__ dinv, float* __restrict__ H2s) {
    __shared__ float Ws[32 * 32];
    __shared__ float xs[32 * 32];
    int t = threadIdx.x;
    ((float4*)Ws)[t] = ((const float4*)W2)[t];
    int row0 = blockIdx.x * 32;
    ((float4*)xs)[t] = ((const float4*)(h1 + (size_t)row0 * 32))[t];
    __syncthreads();
    int col = t & 31;
    int rb = (t >> 5) * 4;
    float a0 = 0.f, a1 = 0.f, a2 = 0.f, a3 = 0.f;
#pragma unroll
    for (int k = 0; k < 32; k++) {
        float w = Ws[k * 32 + col];
        a0 += xs[(rb + 0) * 32 + k] * w;
        a1 += xs[(rb + 1) * 32 + k] * w;
        a2 += xs[(rb + 2) * 32 + k] * w;
        a3 += xs[(rb + 3) * 32 + k] * w;
    }
    int r = row0 + rb;
    float* o = H2s + (size_t)r * 32 + col;
    o[0]  = a0 * dinv[r + 0];
    o[32] = a1 * dinv[r + 1];
    o[64] = a2 * dinv[r + 2];
    o[96] = a3 * dinv[r + 3];
}

// ---------- layer-1 aggregation: one wave per dst node, 16 edges in flight ----
// lanes: q = lane>>4 (edge slot), f2 = lane&15 (float2 feature pair)
// h1[dst] = relu( (sum_e Hs[src_e] + Hs[dst]) * dinv[dst] + b )
__global__ void k_gather1(const float* __restrict__ Hs, const float* __restrict__ dinv,
                          const int* __restrict__ rp, const int* __restrict__ csr,
                          const float* __restrict__ bias, float* __restrict__ hout) {
    int wid = (blockIdx.x * 256 + threadIdx.x) >> 6;
    if (wid >= N_NODES) return;
    int lane = threadIdx.x & 63;
    int f2 = lane & 15;
    int q = lane >> 4;
    int beg = rp[wid], end = rp[wid + 1];
    float ax = 0.f, ay = 0.f;
    int e = beg + q;
    for (; e + 12 < end; e += 16) {
        int s0 = csr[e];
        int s1 = csr[e + 4];
        int s2 = csr[e + 8];
        int s3 = csr[e + 12];
        float2 h0 = *(const float2*)(Hs + (size_t)s0 * 32 + f2 * 2);
        float2 h1 = *(const float2*)(Hs + (size_t)s1 * 32 + f2 * 2);
        float2 h2 = *(const float2*)(Hs + (size_t)s2 * 32 + f2 * 2);
        float2 h3 = *(const float2*)(Hs + (size_t)s3 * 32 + f2 * 2);
        ax += h0.x + h1.x + h2.x + h3.x;
        ay += h0.y + h1.y + h2.y + h3.y;
    }
    for (; e < end; e += 4) {
        int s = csr[e];
        float2 h = *(const float2*)(Hs + (size_t)s * 32 + f2 * 2);
        ax += h.x; ay += h.y;
    }
    ax += __shfl_xor(ax, 16); ay += __shfl_xor(ay, 16);
    ax += __shfl_xor(ax, 32); ay += __shfl_xor(ay, 32);
    if (q == 0) {
        float di = dinv[wid];
        float2 hw = *(const float2*)(Hs + (size_t)wid * 32 + f2 * 2);
        float2 bb = *(const float2*)(bias + f2 * 2);
        float2 o;
        o.x = fmaxf((ax + hw.x) * di + bb.x, 0.f);
        o.y = fmaxf((ay + hw.y) * di + bb.y, 0.f);
        *(float2*)(hout + (size_t)wid * 32 + f2 * 2) = o;
    }
}

// ---------- layer-2 aggregation fused with mean-pool numerator ----------
__global__ void k_gather2(const float* __restrict__ Hs, const float* __restrict__ dinv,
                          const int* __restrict__ rp, const int* __restrict__ csr,
                          const float* __restrict__ bias, const int* __restrict__ batch,
                          float* __restrict__ pool) {
    int wid = (blockIdx.x * 256 + threadIdx.x) >> 6;
    if (wid >= N_NODES) return;
    int lane = threadIdx.x & 63;
    int f2 = lane & 15;
    int q = lane >> 4;
    int beg = rp[wid], end = rp[wid + 1];
    float ax = 0.f, ay = 0.f;
    int e = beg + q;
    for (; e + 12 < end; e += 16) {
        int s0 = csr[e];
        int s1 = csr[e + 4];
        int s2 = csr[e + 8];
        int s3 = csr[e + 12];
        float2 h0 = *(const float2*)(Hs + (size_t)s0 * 32 + f2 * 2);
        float2 h1 = *(const float2*)(Hs + (size_t)s1 * 32 + f2 * 2);
        float2 h2 = *(const float2*)(Hs + (size_t)s2 * 32 + f2 * 2);
        float2 h3 = *(const float2*)(Hs + (size_t)s3 * 32 + f2 * 2);
        ax += h0.x + h1.x + h2.x + h3.x;
        ay += h0.y + h1.y + h2.y + h3.y;
    }
    for (; e < end; e += 4) {
        int s = csr[e];
        float2 h = *(const float2*)(Hs + (size_t)s * 32 + f2 * 2);
        ax += h.x; ay += h.y;
    }
    ax += __shfl_xor(ax, 16); ay += __shfl_xor(ay, 16);
    ax += __shfl_xor(ax, 32); ay += __shfl_xor(ay, 32);
    if (q == 0) {
        float di = dinv[wid];
        float2 hw = *(const float2*)(Hs + (size_t)wid * 32 + f2 * 2);
        float2 bb = *(const float2*)(bias + f2 * 2);
        float vx = fmaxf((ax + hw.x) * di + bb.x, 0.f);
        float vy = fmaxf((ay + hw.y) * di + bb.y, 0.f);
        int g = batch[wid];
        atomicAdd(&pool[(size_t)g * 32 + f2 * 2 + 0], vx);
        atomicAdd(&pool[(size_t)g * 32 + f2 * 2 + 1], vy);
    }
}

// ---------- head ----------
__global__ void k_final(const float* __restrict__ pool, const int* __restrict__ cnt,
                        const float* __restrict__ Wl, const float* __restrict__ bl,
                        float* __restrict__ out) {
    int g = blockIdx.x * 256 + threadIdx.x;
    if (g >= N_GRAPHS) return;
    float inv = 1.0f / fmaxf((float)cnt[g], 1.0f);
    float a0 = bl[0], a1 = bl[1];
#pragma unroll
    for (int f = 0; f < 32; f++) {
        float p = pool[g * 32 + f] * inv;
        a0 += p * Wl[f * 2 + 0];
        a1 += p * Wl[f * 2 + 1];
    }
    out[g * 2 + 0] = a0;
    out[g * 2 + 1] = a1;
}

extern "C" void kernel_launch(void* const* d_in, const int* in_sizes, int n_in,
                              void* d_out, int out_size, void* d_ws, size_t ws_size,
                              hipStream_t stream) {
    const float* x    = (const float*)d_in[0];
    const int*   ei   = (const int*)d_in[1];
    const int*   batch= (const int*)d_in[2];
    const float* W1   = (const float*)d_in[3];
    const float* b1   = (const float*)d_in[4];
    const float* W2   = (const float*)d_in[5];
    const float* b2   = (const float*)d_in[6];
    const float* Wl   = (const float*)d_in[7];
    const float* bl   = (const float*)d_in[8];
    float* out = (float*)d_out;

    char* w = (char*)d_ws;
    size_t off = 0;
    auto take = [&](size_t bytes) -> char* {
        char* p = w + off;
        off = (off + bytes + 255) & ~(size_t)255;
        return p;
    };
    float*    H1s    = (float*)take((size_t)N_NODES * 32 * 4);
    float*    h1     = (float*)take((size_t)N_NODES * 32 * 4);
    // packed (E*4B) and H2s (N*32*4B) alias: disjoint lifetimes.
    char*     shared = take((size_t)N_EDGES * 4);
    unsigned* packed = (unsigned*)shared;
    float*    H2s    = (float*)shared;
    int*      csr    = (int*)  take((size_t)N_EDGES * 4);
    float*    dinv   = (float*)take((size_t)N_NODES * 4);
    int*      rp     = (int*)  take((size_t)(N_NODES + 1) * 4);
    int*      gtot   = (int*)  take((size_t)(NB + 1) * 4);
    int*      base   = (int*)  take((size_t)(NB + 1) * 4);
    int*      gcur   = (int*)  take((size_t)(NB + 1) * 4);
    float*    pool   = (float*)take((size_t)N_GRAPHS * 32 * 4);
    int*      cnt    = (int*)  take((size_t)N_GRAPHS * 4);

    hipMemsetAsync(gtot, 0, (size_t)(NB + 1) * 4, stream);
    hipMemsetAsync(pool, 0, (size_t)N_GRAPHS * 32 * 4, stream);
    hipMemsetAsync(cnt, 0, (size_t)N_GRAPHS * 4, stream);

    k_hist   <<<512, 256, 0, stream>>>(ei, gtot);
    k_bscan  <<<1, 512, 0, stream>>>(gtot, base, gcur);
    k_binfill<<<FILL_BLOCKS, 256, 0, stream>>>(ei, gcur, packed);
    k_csr    <<<NB, 256, 0, stream>>>(packed, base, batch, rp, dinv, csr, cnt);
    k_gemm1  <<<N_NODES / 32, 256, 0, stream>>>(x, W1, dinv, H1s);
    k_gather1<<<N_NODES / 4, 256, 0, stream>>>(H1s, dinv, rp, csr, b1, h1);
    k_gemm2  <<<N_NODES / 32, 256, 0, stream>>>(h1, W2, dinv, H2s);
    k_gather2<<<N_NODES / 4, 256, 0, stream>>>(H2s, dinv, rp, csr, b2, batch, pool);
    k_final  <<<2, 256, 0, stream>>>(pool, cnt, Wl, bl, out);
}

// Round 4
// 470.934 us; speedup vs baseline: 1.9605x; 1.0220x over previous
//
#include <hip/hip_runtime.h>
#include <hip/hip_bf16.h>

#define N_NODES 100000
#define N_EDGES 3200000
#define N_GRAPHS 512
#define NB 391                 // dst buckets of 256 nodes
#define FILL_CHUNK 16384
#define FILL_BLOCKS ((N_EDGES + FILL_CHUNK - 1) / FILL_CHUNK)   // 196

__device__ __forceinline__ float blo(unsigned v) { return __uint_as_float(v << 16); }
__device__ __forceinline__ float bhi(unsigned v) { return __uint_as_float(v & 0xffff0000u); }

// ---------- pass 1: global bucket histogram (bucket = dst >> 8) ----------
__global__ void k_hist(const int* __restrict__ ei, int* __restrict__ gtot) {
    __shared__ int h[NB];
    int t = threadIdx.x;
    for (int i = t; i < NB; i += 256) h[i] = 0;
    __syncthreads();
    int stride = gridDim.x * 256;
    for (int e = blockIdx.x * 256 + t; e < N_EDGES; e += stride)
        atomicAdd(&h[ei[N_EDGES + e] >> 8], 1);
    __syncthreads();
    for (int i = t; i < NB; i += 256) if (h[i]) atomicAdd(&gtot[i], h[i]);
}

// ---------- pass 2: exclusive scan of bucket totals ----------
__global__ void k_bscan(const int* __restrict__ gtot, int* __restrict__ base,
                        int* __restrict__ cursor) {
    __shared__ int sd[512];
    int t = threadIdx.x;
    int v = (t < NB) ? gtot[t] : 0;
    sd[t] = v; __syncthreads();
    for (int off = 1; off < 512; off <<= 1) {
        int x = (t >= off) ? sd[t - off] : 0;
        __syncthreads(); sd[t] += x; __syncthreads();
    }
    int excl = sd[t] - v;
    if (t < NB) { base[t] = excl; cursor[t] = excl; }
    if (t == NB - 1) base[NB] = excl + v;   // == N_EDGES
}

// ---------- pass 3: bin edges into buckets, packed (dstlocal<<17 | src) ----------
__global__ void k_binfill(const int* __restrict__ ei, int* __restrict__ gcur,
                          unsigned* __restrict__ packed) {
    __shared__ int h[NB];
    __shared__ int base[NB];
    int t = threadIdx.x;
    for (int i = t; i < NB; i += 256) h[i] = 0;
    __syncthreads();
    int s0 = blockIdx.x * FILL_CHUNK;
    int s1 = min(s0 + FILL_CHUNK, N_EDGES);
    for (int e = s0 + t; e < s1; e += 256)
        atomicAdd(&h[ei[N_EDGES + e] >> 8], 1);
    __syncthreads();
    for (int i = t; i < NB; i += 256) {
        int c = h[i];
        base[i] = c ? atomicAdd(&gcur[i], c) : 0;
        h[i] = 0;
    }
    __syncthreads();
    for (int e = s0 + t; e < s1; e += 256) {
        int dst = ei[N_EDGES + e];
        int bk = dst >> 8;
        int pos = base[bk] + atomicAdd(&h[bk], 1);
        packed[pos] = (unsigned)ei[e] | (((unsigned)dst & 255u) << 17);
    }
}

// ---------- pass 4: per-bucket deg/rp/dinv/cnt + exact CSR fill ----------
__global__ void k_csr(const unsigned* __restrict__ packed, const int* __restrict__ base,
                      const int* __restrict__ batch,
                      int* __restrict__ rp, float* __restrict__ dinv,
                      int* __restrict__ csr, int* __restrict__ cnt) {
    __shared__ int deg[256];
    __shared__ int sd[256];
    __shared__ int cur[256];
    int t = threadIdx.x;
    int b = blockIdx.x;
    deg[t] = 0;
    __syncthreads();
    int bb = base[b], be = base[b + 1];
    for (int e = bb + t; e < be; e += 256)
        atomicAdd(&deg[packed[e] >> 17], 1);
    __syncthreads();
    int d = deg[t];
    sd[t] = d; __syncthreads();
    for (int off = 1; off < 256; off <<= 1) {
        int x = (t >= off) ? sd[t - off] : 0;
        __syncthreads(); sd[t] += x; __syncthreads();
    }
    int pos0 = bb + sd[t] - d;
    cur[t] = pos0;
    int node = b * 256 + t;
    if (node < N_NODES) {
        rp[node] = pos0;
        dinv[node] = rsqrtf((float)d + 1.0f);
        atomicAdd(&cnt[batch[node]], 1);
    }
    if (node == N_NODES - 1) rp[N_NODES] = N_EDGES;
    __syncthreads();
    for (int e = bb + t; e < be; e += 256) {
        unsigned p = packed[e];
        int pos = atomicAdd(&cur[p >> 17], 1);
        csr[pos] = (int)(p & 0x1FFFFu);
    }
}

// ---------- H1s = bf16( (x @ W1) * dinv[row] )  ([100000,128] @ [128,32]) ----------
__global__ void k_gemm1(const float* __restrict__ x, const float* __restrict__ W1,
                        const float* __restrict__ dinv, __hip_bfloat16* __restrict__ H1s) {
    __shared__ float Ws[128 * 32];
    __shared__ float xs[32 * 128];
    int t = threadIdx.x;
    const float4* W4 = (const float4*)W1;
    float4* Ws4 = (float4*)Ws;
#pragma unroll
    for (int i = 0; i < 4; i++) Ws4[t + 256 * i] = W4[t + 256 * i];
    int row0 = blockIdx.x * 32;
    const float4* x4 = (const float4*)(x + (size_t)row0 * 128);
    float4* xs4 = (float4*)xs;
#pragma unroll
    for (int i = 0; i < 4; i++) xs4[t + 256 * i] = x4[t + 256 * i];
    __syncthreads();
    int col = t & 31;
    int rb = (t >> 5) * 4;
    float a0 = 0.f, a1 = 0.f, a2 = 0.f, a3 = 0.f;
#pragma unroll 8
    for (int k = 0; k < 128; k++) {
        float w = Ws[k * 32 + col];
        a0 += xs[(rb + 0) * 128 + k] * w;
        a1 += xs[(rb + 1) * 128 + k] * w;
        a2 += xs[(rb + 2) * 128 + k] * w;
        a3 += xs[(rb + 3) * 128 + k] * w;
    }
    int r = row0 + rb;
    __hip_bfloat16* o = H1s + (size_t)r * 32 + col;
    o[0]  = __float2bfloat16(a0 * dinv[r + 0]);
    o[32] = __float2bfloat16(a1 * dinv[r + 1]);
    o[64] = __float2bfloat16(a2 * dinv[r + 2]);
    o[96] = __float2bfloat16(a3 * dinv[r + 3]);
}

// ---------- H2s = bf16( (h1 @ W2) * dinv[row] )  ([100000,32] @ [32,32]) ----------
__global__ void k_gemm2(const float* __restrict__ h1, const float* __restrict__ W2,
                        const float* __restrict__ dinv, __hip_bfloat16* __restrict__ H2s) {
    __shared__ float Ws[32 * 32];
    __shared__ float xs[32 * 32];
    int t = threadIdx.x;
    ((float4*)Ws)[t] = ((const float4*)W2)[t];
    int row0 = blockIdx.x * 32;
    ((float4*)xs)[t] = ((const float4*)(h1 + (size_t)row0 * 32))[t];
    __syncthreads();
    int col = t & 31;
    int rb = (t >> 5) * 4;
    float a0 = 0.f, a1 = 0.f, a2 = 0.f, a3 = 0.f;
#pragma unroll
    for (int k = 0; k < 32; k++) {
        float w = Ws[k * 32 + col];
        a0 += xs[(rb + 0) * 32 + k] * w;
        a1 += xs[(rb + 1) * 32 + k] * w;
        a2 += xs[(rb + 2) * 32 + k] * w;
        a3 += xs[(rb + 3) * 32 + k] * w;
    }
    int r = row0 + rb;
    __hip_bfloat16* o = H2s + (size_t)r * 32 + col;
    o[0]  = __float2bfloat16(a0 * dinv[r + 0]);
    o[32] = __float2bfloat16(a1 * dinv[r + 1]);
    o[64] = __float2bfloat16(a2 * dinv[r + 2]);
    o[96] = __float2bfloat16(a3 * dinv[r + 3]);
}

// ---------- layer-1 aggregation: one wave per dst node, 16 edges in flight ----
// Hs rows are 32 bf16 = 64 B. lane: q = lane>>4 (edge slot), f2 = lane&15 (bf16 pair)
// h1[dst] = relu( (sum_e Hs[src_e] + Hs[dst]) * dinv[dst] + b )
__global__ void k_gather1(const __hip_bfloat16* __restrict__ Hs, const float* __restrict__ dinv,
                          const int* __restrict__ rp, const int* __restrict__ csr,
                          const float* __restrict__ bias, float* __restrict__ hout) {
    int wid = (blockIdx.x * 256 + threadIdx.x) >> 6;
    if (wid >= N_NODES) return;
    const unsigned* H32 = (const unsigned*)Hs;   // row stride 16 uints
    int lane = threadIdx.x & 63;
    int f2 = lane & 15;
    int q = lane >> 4;
    int beg = rp[wid], end = rp[wid + 1];
    float ax = 0.f, ay = 0.f;
    int e = beg + q;
    for (; e + 12 < end; e += 16) {
        int s0 = csr[e];
        int s1 = csr[e + 4];
        int s2 = csr[e + 8];
        int s3 = csr[e + 12];
        unsigned v0 = H32[(size_t)s0 * 16 + f2];
        unsigned v1 = H32[(size_t)s1 * 16 + f2];
        unsigned v2 = H32[(size_t)s2 * 16 + f2];
        unsigned v3 = H32[(size_t)s3 * 16 + f2];
        ax += blo(v0) + blo(v1) + blo(v2) + blo(v3);
        ay += bhi(v0) + bhi(v1) + bhi(v2) + bhi(v3);
    }
    for (; e < end; e += 4) {
        unsigned v = H32[(size_t)csr[e] * 16 + f2];
        ax += blo(v); ay += bhi(v);
    }
    ax += __shfl_xor(ax, 16); ay += __shfl_xor(ay, 16);
    ax += __shfl_xor(ax, 32); ay += __shfl_xor(ay, 32);
    if (q == 0) {
        float di = dinv[wid];
        unsigned vw = H32[(size_t)wid * 16 + f2];
        float2 bb = *(const float2*)(bias + f2 * 2);
        float2 o;
        o.x = fmaxf((ax + blo(vw)) * di + bb.x, 0.f);
        o.y = fmaxf((ay + bhi(vw)) * di + bb.y, 0.f);
        *(float2*)(hout + (size_t)wid * 32 + f2 * 2) = o;
    }
}

// ---------- layer-2 aggregation fused with mean-pool numerator ----------
__global__ void k_gather2(const __hip_bfloat16* __restrict__ Hs, const float* __restrict__ dinv,
                          const int* __restrict__ rp, const int* __restrict__ csr,
                          const float* __restrict__ bias, const int* __restrict__ batch,
                          float* __restrict__ pool) {
    int wid = (blockIdx.x * 256 + threadIdx.x) >> 6;
    if (wid >= N_NODES) return;
    const unsigned* H32 = (const unsigned*)Hs;
    int lane = threadIdx.x & 63;
    int f2 = lane & 15;
    int q = lane >> 4;
    int beg = rp[wid], end = rp[wid + 1];
    float ax = 0.f, ay = 0.f;
    int e = beg + q;
    for (; e + 12 < end; e += 16) {
        int s0 = csr[e];
        int s1 = csr[e + 4];
        int s2 = csr[e + 8];
        int s3 = csr[e + 12];
        unsigned v0 = H32[(size_t)s0 * 16 + f2];
        unsigned v1 = H32[(size_t)s1 * 16 + f2];
        unsigned v2 = H32[(size_t)s2 * 16 + f2];
        unsigned v3 = H32[(size_t)s3 * 16 + f2];
        ax += blo(v0) + blo(v1) + blo(v2) + blo(v3);
        ay += bhi(v0) + bhi(v1) + bhi(v2) + bhi(v3);
    }
    for (; e < end; e += 4) {
        unsigned v = H32[(size_t)csr[e] * 16 + f2];
        ax += blo(v); ay += bhi(v);
    }
    ax += __shfl_xor(ax, 16); ay += __shfl_xor(ay, 16);
    ax += __shfl_xor(ax, 32); ay += __shfl_xor(ay, 32);
    if (q == 0) {
        float di = dinv[wid];
        unsigned vw = H32[(size_t)wid * 16 + f2];
        float2 bb = *(const float2*)(bias + f2 * 2);
        float vx = fmaxf((ax + blo(vw)) * di + bb.x, 0.f);
        float vy = fmaxf((ay + bhi(vw)) * di + bb.y, 0.f);
        int g = batch[wid];
        atomicAdd(&pool[(size_t)g * 32 + f2 * 2 + 0], vx);
        atomicAdd(&pool[(size_t)g * 32 + f2 * 2 + 1], vy);
    }
}

// ---------- head ----------
__global__ void k_final(const float* __restrict__ pool, const int* __restrict__ cnt,
                        const float* __restrict__ Wl, const float* __restrict__ bl,
                        float* __restrict__ out) {
    int g = blockIdx.x * 256 + threadIdx.x;
    if (g >= N_GRAPHS) return;
    float inv = 1.0f / fmaxf((float)cnt[g], 1.0f);
    float a0 = bl[0], a1 = bl[1];
#pragma unroll
    for (int f = 0; f < 32; f++) {
        float p = pool[g * 32 + f] * inv;
        a0 += p * Wl[f * 2 + 0];
        a1 += p * Wl[f * 2 + 1];
    }
    out[g * 2 + 0] = a0;
    out[g * 2 + 1] = a1;
}

extern "C" void kernel_launch(void* const* d_in, const int* in_sizes, int n_in,
                              void* d_out, int out_size, void* d_ws, size_t ws_size,
                              hipStream_t stream) {
    const float* x    = (const float*)d_in[0];
    const int*   ei   = (const int*)d_in[1];
    const int*   batch= (const int*)d_in[2];
    const float* W1   = (const float*)d_in[3];
    const float* b1   = (const float*)d_in[4];
    const float* W2   = (const float*)d_in[5];
    const float* b2   = (const float*)d_in[6];
    const float* Wl   = (const float*)d_in[7];
    const float* bl   = (const float*)d_in[8];
    float* out = (float*)d_out;

    char* w = (char*)d_ws;
    size_t off = 0;
    auto take = [&](size_t bytes) -> char* {
        char* p = w + off;
        off = (off + bytes + 255) & ~(size_t)255;
        return p;
    };
    __hip_bfloat16* H1s = (__hip_bfloat16*)take((size_t)N_NODES * 32 * 2);
    float*          h1  = (float*)take((size_t)N_NODES * 32 * 4);
    // packed (E*4B) and H2s (N*32*2B) alias: disjoint lifetimes.
    char*           shared = take((size_t)N_EDGES * 4);
    unsigned*       packed = (unsigned*)shared;
    __hip_bfloat16* H2s    = (__hip_bfloat16*)shared;
    int*      csr    = (int*)  take((size_t)N_EDGES * 4);
    float*    dinv   = (float*)take((size_t)N_NODES * 4);
    int*      rp     = (int*)  take((size_t)(N_NODES + 1) * 4);
    int*      gtot   = (int*)  take((size_t)(NB + 1) * 4);
    int*      base   = (int*)  take((size_t)(NB + 1) * 4);
    int*      gcur   = (int*)  take((size_t)(NB + 1) * 4);
    float*    pool   = (float*)take((size_t)N_GRAPHS * 32 * 4);
    int*      cnt    = (int*)  take((size_t)N_GRAPHS * 4);

    hipMemsetAsync(gtot, 0, (size_t)(NB + 1) * 4, stream);
    hipMemsetAsync(pool, 0, (size_t)N_GRAPHS * 32 * 4, stream);
    hipMemsetAsync(cnt, 0, (size_t)N_GRAPHS * 4, stream);

    k_hist   <<<512, 256, 0, stream>>>(ei, gtot);
    k_bscan  <<<1, 512, 0, stream>>>(gtot, base, gcur);
    k_binfill<<<FILL_BLOCKS, 256, 0, stream>>>(ei, gcur, packed);
    k_csr    <<<NB, 256, 0, stream>>>(packed, base, batch, rp, dinv, csr, cnt);
    k_gemm1  <<<N_NODES / 32, 256, 0, stream>>>(x, W1, dinv, H1s);
    k_gather1<<<N_NODES / 4, 256, 0, stream>>>(H1s, dinv, rp, csr, b1, h1);
    k_gemm2  <<<N_NODES / 32, 256, 0, stream>>>(h1, W2, dinv, H2s);
    k_gather2<<<N_NODES / 4, 256, 0, stream>>>(H2s, dinv, rp, csr, b2, batch, pool);
    k_final  <<<2, 256, 0, stream>>>(pool, cnt, Wl, bl, out);
}

// Round 5
// 441.948 us; speedup vs baseline: 2.0891x; 1.0656x over previous
//
#include <hip/hip_runtime.h>
#include <hip/hip_bf16.h>

#define N_NODES 100000
#define N_EDGES 3200000
#define N_GRAPHS 512
#define NB 391                 // dst buckets of 256 nodes
#define FILL_CHUNK 16384
#define FILL_BLOCKS ((N_EDGES + FILL_CHUNK - 1) / FILL_CHUNK)   // 196
#define BCAP 10240             // LDS staging cap for one bucket (40 KB)

__device__ __forceinline__ float blo(unsigned v) { return __uint_as_float(v << 16); }
__device__ __forceinline__ float bhi(unsigned v) { return __uint_as_float(v & 0xffff0000u); }

// ---------- pass 1: global bucket histogram (bucket = dst >> 8) ----------
__global__ void k_hist(const int* __restrict__ ei, int* __restrict__ gtot) {
    __shared__ int h[NB];
    int t = threadIdx.x;
    for (int i = t; i < NB; i += 256) h[i] = 0;
    __syncthreads();
    int stride = gridDim.x * 256;
    for (int e = blockIdx.x * 256 + t; e < N_EDGES; e += stride)
        atomicAdd(&h[ei[N_EDGES + e] >> 8], 1);
    __syncthreads();
    for (int i = t; i < NB; i += 256) if (h[i]) atomicAdd(&gtot[i], h[i]);
}

// ---------- pass 2: exclusive scan of bucket totals ----------
__global__ void k_bscan(const int* __restrict__ gtot, int* __restrict__ base,
                        int* __restrict__ cursor) {
    __shared__ int sd[512];
    int t = threadIdx.x;
    int v = (t < NB) ? gtot[t] : 0;
    sd[t] = v; __syncthreads();
    for (int off = 1; off < 512; off <<= 1) {
        int x = (t >= off) ? sd[t - off] : 0;
        __syncthreads(); sd[t] += x; __syncthreads();
    }
    int excl = sd[t] - v;
    if (t < NB) { base[t] = excl; cursor[t] = excl; }
    if (t == NB - 1) base[NB] = excl + v;   // == N_EDGES
}

// ---------- pass 3: bin edges into buckets, packed (dstlocal<<17 | src) ----------
__global__ __launch_bounds__(1024) void k_binfill(const int* __restrict__ ei,
                                                  int* __restrict__ gcur,
                                                  unsigned* __restrict__ packed) {
    __shared__ int h[NB];
    __shared__ int base[NB];
    int t = threadIdx.x;
    for (int i = t; i < NB; i += 1024) h[i] = 0;
    __syncthreads();
    int s0 = blockIdx.x * FILL_CHUNK;
    int s1 = min(s0 + FILL_CHUNK, N_EDGES);
    for (int e = s0 + t; e < s1; e += 1024)
        atomicAdd(&h[ei[N_EDGES + e] >> 8], 1);
    __syncthreads();
    for (int i = t; i < NB; i += 1024) {
        int c = h[i];
        base[i] = c ? atomicAdd(&gcur[i], c) : 0;
        h[i] = 0;
    }
    __syncthreads();
    for (int e = s0 + t; e < s1; e += 1024) {
        int dst = ei[N_EDGES + e];
        int bk = dst >> 8;
        int pos = base[bk] + atomicAdd(&h[bk], 1);
        packed[pos] = (unsigned)ei[e] | (((unsigned)dst & 255u) << 17);
    }
}

// ---------- pass 4: per-bucket deg/rp/dinv/cnt + exact CSR fill ----------
// 1024 threads/block; bucket's packed entries staged in LDS (one global read).
__global__ __launch_bounds__(1024) void k_csr(const unsigned* __restrict__ packed,
                                              const int* __restrict__ base,
                                              const int* __restrict__ batch,
                                              int* __restrict__ rp, float* __restrict__ dinv,
                                              int* __restrict__ csr, int* __restrict__ cnt) {
    __shared__ unsigned ebuf[BCAP];   // 40 KB
    __shared__ int deg[256];
    __shared__ int sd[256];
    __shared__ int cur[256];
    int t = threadIdx.x;
    int b = blockIdx.x;
    if (t < 256) deg[t] = 0;
    __syncthreads();
    int bb = base[b], be = base[b + 1];
    int n = be - bb;
    for (int i = t; i < n; i += 1024) {
        unsigned p = packed[bb + i];
        if (i < BCAP) ebuf[i] = p;
        atomicAdd(&deg[p >> 17], 1);
    }
    __syncthreads();
    int d = (t < 256) ? deg[t] : 0;
    if (t < 256) sd[t] = d;
    __syncthreads();
    for (int off = 1; off < 256; off <<= 1) {
        int x = (t >= off && t < 256) ? sd[t - off] : 0;
        __syncthreads();
        if (t < 256) sd[t] += x;
        __syncthreads();
    }
    if (t < 256) {
        int pos0 = bb + sd[t] - d;
        cur[t] = pos0;
        int node = b * 256 + t;
        if (node < N_NODES) {
            rp[node] = pos0;
            dinv[node] = rsqrtf((float)d + 1.0f);
            atomicAdd(&cnt[batch[node]], 1);
        }
        if (node == N_NODES - 1) rp[N_NODES] = N_EDGES;
    }
    __syncthreads();
    for (int i = t; i < n; i += 1024) {
        unsigned p = (i < BCAP) ? ebuf[i] : packed[bb + i];
        int pos = atomicAdd(&cur[p >> 17], 1);
        csr[pos] = (int)(p & 0x1FFFFu);
    }
}

// ---------- H1s = bf16( (x @ W1) * dinv[row] )  ([100000,128] @ [128,32]) ----------
__global__ void k_gemm1(const float* __restrict__ x, const float* __restrict__ W1,
                        const float* __restrict__ dinv, __hip_bfloat16* __restrict__ H1s) {
    __shared__ float Ws[128 * 32];
    __shared__ float xs[32 * 128];
    int t = threadIdx.x;
    const float4* W4 = (const float4*)W1;
    float4* Ws4 = (float4*)Ws;
#pragma unroll
    for (int i = 0; i < 4; i++) Ws4[t + 256 * i] = W4[t + 256 * i];
    int row0 = blockIdx.x * 32;
    const float4* x4 = (const float4*)(x + (size_t)row0 * 128);
    float4* xs4 = (float4*)xs;
#pragma unroll
    for (int i = 0; i < 4; i++) xs4[t + 256 * i] = x4[t + 256 * i];
    __syncthreads();
    int col = t & 31;
    int rb = (t >> 5) * 4;
    float a0 = 0.f, a1 = 0.f, a2 = 0.f, a3 = 0.f;
#pragma unroll 8
    for (int k = 0; k < 128; k++) {
        float w = Ws[k * 32 + col];
        a0 += xs[(rb + 0) * 128 + k] * w;
        a1 += xs[(rb + 1) * 128 + k] * w;
        a2 += xs[(rb + 2) * 128 + k] * w;
        a3 += xs[(rb + 3) * 128 + k] * w;
    }
    int r = row0 + rb;
    __hip_bfloat16* o = H1s + (size_t)r * 32 + col;
    o[0]  = __float2bfloat16(a0 * dinv[r + 0]);
    o[32] = __float2bfloat16(a1 * dinv[r + 1]);
    o[64] = __float2bfloat16(a2 * dinv[r + 2]);
    o[96] = __float2bfloat16(a3 * dinv[r + 3]);
}

// ---------- H2s = bf16( (h1 @ W2) * dinv[row] )  ([100000,32] @ [32,32]) ----------
__global__ void k_gemm2(const float* __restrict__ h1, const float* __restrict__ W2,
                        const float* __restrict__ dinv, __hip_bfloat16* __restrict__ H2s) {
    __shared__ float Ws[32 * 32];
    __shared__ float xs[32 * 32];
    int t = threadIdx.x;
    ((float4*)Ws)[t] = ((const float4*)W2)[t];
    int row0 = blockIdx.x * 32;
    ((float4*)xs)[t] = ((const float4*)(h1 + (size_t)row0 * 32))[t];
    __syncthreads();
    int col = t & 31;
    int rb = (t >> 5) * 4;
    float a0 = 0.f, a1 = 0.f, a2 = 0.f, a3 = 0.f;
#pragma unroll
    for (int k = 0; k < 32; k++) {
        float w = Ws[k * 32 + col];
        a0 += xs[(rb + 0) * 32 + k] * w;
        a1 += xs[(rb + 1) * 32 + k] * w;
        a2 += xs[(rb + 2) * 32 + k] * w;
        a3 += xs[(rb + 3) * 32 + k] * w;
    }
    int r = row0 + rb;
    __hip_bfloat16* o = H2s + (size_t)r * 32 + col;
    o[0]  = __float2bfloat16(a0 * dinv[r + 0]);
    o[32] = __float2bfloat16(a1 * dinv[r + 1]);
    o[64] = __float2bfloat16(a2 * dinv[r + 2]);
    o[96] = __float2bfloat16(a3 * dinv[r + 3]);
}

// ---------- layer-1 aggregation: one wave per dst node, 16 edges in flight ----
__global__ void k_gather1(const __hip_bfloat16* __restrict__ Hs, const float* __restrict__ dinv,
                          const int* __restrict__ rp, const int* __restrict__ csr,
                          const float* __restrict__ bias, float* __restrict__ hout) {
    int wid = (blockIdx.x * 256 + threadIdx.x) >> 6;
    if (wid >= N_NODES) return;
    const unsigned* H32 = (const unsigned*)Hs;   // row stride 16 uints
    int lane = threadIdx.x & 63;
    int f2 = lane & 15;
    int q = lane >> 4;
    int beg = rp[wid], end = rp[wid + 1];
    float ax = 0.f, ay = 0.f;
    int e = beg + q;
    for (; e + 12 < end; e += 16) {
        int s0 = csr[e];
        int s1 = csr[e + 4];
        int s2 = csr[e + 8];
        int s3 = csr[e + 12];
        unsigned v0 = H32[(size_t)s0 * 16 + f2];
        unsigned v1 = H32[(size_t)s1 * 16 + f2];
        unsigned v2 = H32[(size_t)s2 * 16 + f2];
        unsigned v3 = H32[(size_t)s3 * 16 + f2];
        ax += blo(v0) + blo(v1) + blo(v2) + blo(v3);
        ay += bhi(v0) + bhi(v1) + bhi(v2) + bhi(v3);
    }
    for (; e < end; e += 4) {
        unsigned v = H32[(size_t)csr[e] * 16 + f2];
        ax += blo(v); ay += bhi(v);
    }
    ax += __shfl_xor(ax, 16); ay += __shfl_xor(ay, 16);
    ax += __shfl_xor(ax, 32); ay += __shfl_xor(ay, 32);
    if (q == 0) {
        float di = dinv[wid];
        unsigned vw = H32[(size_t)wid * 16 + f2];
        float2 bb = *(const float2*)(bias + f2 * 2);
        float2 o;
        o.x = fmaxf((ax + blo(vw)) * di + bb.x, 0.f);
        o.y = fmaxf((ay + bhi(vw)) * di + bb.y, 0.f);
        *(float2*)(hout + (size_t)wid * 32 + f2 * 2) = o;
    }
}

// ---------- layer-2 aggregation fused with mean-pool numerator ----------
__global__ void k_gather2(const __hip_bfloat16* __restrict__ Hs, const float* __restrict__ dinv,
                          const int* __restrict__ rp, const int* __restrict__ csr,
                          const float* __restrict__ bias, const int* __restrict__ batch,
                          float* __restrict__ pool) {
    int wid = (blockIdx.x * 256 + threadIdx.x) >> 6;
    if (wid >= N_NODES) return;
    const unsigned* H32 = (const unsigned*)Hs;
    int lane = threadIdx.x & 63;
    int f2 = lane & 15;
    int q = lane >> 4;
    int beg = rp[wid], end = rp[wid + 1];
    float ax = 0.f, ay = 0.f;
    int e = beg + q;
    for (; e + 12 < end; e += 16) {
        int s0 = csr[e];
        int s1 = csr[e + 4];
        int s2 = csr[e + 8];
        int s3 = csr[e + 12];
        unsigned v0 = H32[(size_t)s0 * 16 + f2];
        unsigned v1 = H32[(size_t)s1 * 16 + f2];
        unsigned v2 = H32[(size_t)s2 * 16 + f2];
        unsigned v3 = H32[(size_t)s3 * 16 + f2];
        ax += blo(v0) + blo(v1) + blo(v2) + blo(v3);
        ay += bhi(v0) + bhi(v1) + bhi(v2) + bhi(v3);
    }
    for (; e < end; e += 4) {
        unsigned v = H32[(size_t)csr[e] * 16 + f2];
        ax += blo(v); ay += bhi(v);
    }
    ax += __shfl_xor(ax, 16); ay += __shfl_xor(ay, 16);
    ax += __shfl_xor(ax, 32); ay += __shfl_xor(ay, 32);
    if (q == 0) {
        float di = dinv[wid];
        unsigned vw = H32[(size_t)wid * 16 + f2];
        float2 bb = *(const float2*)(bias + f2 * 2);
        float vx = fmaxf((ax + blo(vw)) * di + bb.x, 0.f);
        float vy = fmaxf((ay + bhi(vw)) * di + bb.y, 0.f);
        int g = batch[wid];
        atomicAdd(&pool[(size_t)g * 32 + f2 * 2 + 0], vx);
        atomicAdd(&pool[(size_t)g * 32 + f2 * 2 + 1], vy);
    }
}

// ---------- head ----------
__global__ void k_final(const float* __restrict__ pool, const int* __restrict__ cnt,
                        const float* __restrict__ Wl, const float* __restrict__ bl,
                        float* __restrict__ out) {
    int g = blockIdx.x * 256 + threadIdx.x;
    if (g >= N_GRAPHS) return;
    float inv = 1.0f / fmaxf((float)cnt[g], 1.0f);
    float a0 = bl[0], a1 = bl[1];
#pragma unroll
    for (int f = 0; f < 32; f++) {
        float p = pool[g * 32 + f] * inv;
        a0 += p * Wl[f * 2 + 0];
        a1 += p * Wl[f * 2 + 1];
    }
    out[g * 2 + 0] = a0;
    out[g * 2 + 1] = a1;
}

extern "C" void kernel_launch(void* const* d_in, const int* in_sizes, int n_in,
                              void* d_out, int out_size, void* d_ws, size_t ws_size,
                              hipStream_t stream) {
    const float* x    = (const float*)d_in[0];
    const int*   ei   = (const int*)d_in[1];
    const int*   batch= (const int*)d_in[2];
    const float* W1   = (const float*)d_in[3];
    const float* b1   = (const float*)d_in[4];
    const float* W2   = (const float*)d_in[5];
    const float* b2   = (const float*)d_in[6];
    const float* Wl   = (const float*)d_in[7];
    const float* bl   = (const float*)d_in[8];
    float* out = (float*)d_out;

    char* w = (char*)d_ws;
    size_t off = 0;
    auto take = [&](size_t bytes) -> char* {
        char* p = w + off;
        off = (off + bytes + 255) & ~(size_t)255;
        return p;
    };
    __hip_bfloat16* H1s = (__hip_bfloat16*)take((size_t)N_NODES * 32 * 2);
    float*          h1  = (float*)take((size_t)N_NODES * 32 * 4);
    // packed (E*4B) and H2s (N*32*2B) alias: disjoint lifetimes.
    char*           shared = take((size_t)N_EDGES * 4);
    unsigned*       packed = (unsigned*)shared;
    __hip_bfloat16* H2s    = (__hip_bfloat16*)shared;
    int*      csr    = (int*)  take((size_t)N_EDGES * 4);
    float*    dinv   = (float*)take((size_t)N_NODES * 4);
    int*      rp     = (int*)  take((size_t)(N_NODES + 1) * 4);
    int*      gtot   = (int*)  take((size_t)(NB + 1) * 4);
    int*      base   = (int*)  take((size_t)(NB + 1) * 4);
    int*      gcur   = (int*)  take((size_t)(NB + 1) * 4);
    float*    pool   = (float*)take((size_t)N_GRAPHS * 32 * 4);
    int*      cnt    = (int*)  take((size_t)N_GRAPHS * 4);

    hipMemsetAsync(gtot, 0, (size_t)(NB + 1) * 4, stream);
    hipMemsetAsync(pool, 0, (size_t)N_GRAPHS * 32 * 4, stream);
    hipMemsetAsync(cnt, 0, (size_t)N_GRAPHS * 4, stream);

    k_hist   <<<512, 256, 0, stream>>>(ei, gtot);
    k_bscan  <<<1, 512, 0, stream>>>(gtot, base, gcur);
    k_binfill<<<FILL_BLOCKS, 1024, 0, stream>>>(ei, gcur, packed);
    k_csr    <<<NB, 1024, 0, stream>>>(packed, base, batch, rp, dinv, csr, cnt);
    k_gemm1  <<<N_NODES / 32, 256, 0, stream>>>(x, W1, dinv, H1s);
    k_gather1<<<N_NODES / 4, 256, 0, stream>>>(H1s, dinv, rp, csr, b1, h1);
    k_gemm2  <<<N_NODES / 32, 256, 0, stream>>>(h1, W2, dinv, H2s);
    k_gather2<<<N_NODES / 4, 256, 0, stream>>>(H2s, dinv, rp, csr, b2, batch, pool);
    k_final  <<<2, 256, 0, stream>>>(pool, cnt, Wl, bl, out);
}

// Round 6
// 411.162 us; speedup vs baseline: 2.2455x; 1.0749x over previous
//
#include <hip/hip_runtime.h>
#include <hip/hip_bf16.h>

#define N_NODES 100000
#define N_EDGES 3200000
#define N_GRAPHS 512
#define NBUK 391               // dst buckets of 256 nodes
#define CAP 10240              // fixed slot capacity per bucket (mean 8184, sigma~90)
#define FILL_CHUNK 16384
#define FILL_BLOCKS ((N_EDGES + FILL_CHUNK - 1) / FILL_CHUNK)   // 196

__device__ __forceinline__ float blo(unsigned v) { return __uint_as_float(v << 16); }
__device__ __forceinline__ float bhi(unsigned v) { return __uint_as_float(v & 0xffff0000u); }

// ---------- pass 1: bin edges into fixed bucket slots, rank-trick (1 LDS atomic/edge) ----
__global__ __launch_bounds__(1024) void k_binfill(const int* __restrict__ ei,
                                                  int* __restrict__ gcnt,
                                                  unsigned* __restrict__ packed) {
    __shared__ int h[NBUK];
    __shared__ int base[NBUK];
    int t = threadIdx.x;
    for (int i = t; i < NBUK; i += 1024) h[i] = 0;
    __syncthreads();
    int s0 = blockIdx.x * FILL_CHUNK;
    int ng = min(FILL_CHUNK, N_EDGES - s0) >> 2;   // 4-entry groups (4096 or 1280)
    const int4* src4 = (const int4*)(ei + s0);
    const int4* dst4 = (const int4*)(ei + N_EDGES + s0);
    int4 sv[4], dv[4];
    int  rk[4][4];
#pragma unroll
    for (int g = 0; g < 4; g++) {
        int gi = t + g * 1024;
        if (gi < ng) {
            sv[g] = src4[gi];
            dv[g] = dst4[gi];
            rk[g][0] = atomicAdd(&h[dv[g].x >> 8], 1);
            rk[g][1] = atomicAdd(&h[dv[g].y >> 8], 1);
            rk[g][2] = atomicAdd(&h[dv[g].z >> 8], 1);
            rk[g][3] = atomicAdd(&h[dv[g].w >> 8], 1);
        }
    }
    __syncthreads();
    for (int i = t; i < NBUK; i += 1024) {
        int c = h[i];
        base[i] = c ? atomicAdd(&gcnt[i], c) : 0;
    }
    __syncthreads();
#pragma unroll
    for (int g = 0; g < 4; g++) {
        int gi = t + g * 1024;
        if (gi < ng) {
            int s[4] = {sv[g].x, sv[g].y, sv[g].z, sv[g].w};
            int d[4] = {dv[g].x, dv[g].y, dv[g].z, dv[g].w};
#pragma unroll
            for (int k = 0; k < 4; k++) {
                int bk = d[k] >> 8;
                int pos = bk * CAP + base[bk] + rk[g][k];
                packed[pos] = (unsigned)s[k] | (((unsigned)d[k] & 255u) << 17);
            }
        }
    }
}

// ---------- pass 2: per-bucket deg/rp/rpe/dinv/cnt + slotted CSR, rank-trick ----------
__global__ __launch_bounds__(1024) void k_csr(const unsigned* __restrict__ packed,
                                              const int* __restrict__ gcnt,
                                              const int* __restrict__ batch,
                                              int* __restrict__ rp, int* __restrict__ rpe,
                                              float* __restrict__ dinv,
                                              int* __restrict__ csr, int* __restrict__ cnt) {
    __shared__ int deg[256];
    __shared__ int sd[256];
    __shared__ int nb0[256];
    int t = threadIdx.x;
    int b = blockIdx.x;
    if (t < 256) deg[t] = 0;
    __syncthreads();
    int n = gcnt[b];
    const unsigned* pb = packed + (size_t)b * CAP;
    unsigned pv[3][4];
    int rk[3][4];
#pragma unroll
    for (int g = 0; g < 3; g++) {
        int i0 = 4 * (t + g * 1024);
        if (i0 < n) {
            if (i0 + 3 < n) {
                uint4 p = *(const uint4*)(pb + i0);
                pv[g][0] = p.x; pv[g][1] = p.y; pv[g][2] = p.z; pv[g][3] = p.w;
            } else {
#pragma unroll
                for (int k = 0; k < 4; k++) pv[g][k] = (i0 + k < n) ? pb[i0 + k] : 0u;
            }
#pragma unroll
            for (int k = 0; k < 4; k++)
                if (i0 + k < n) rk[g][k] = atomicAdd(&deg[pv[g][k] >> 17], 1);
        }
    }
    __syncthreads();
    int d = (t < 256) ? deg[t] : 0;
    if (t < 256) sd[t] = d;
    __syncthreads();
    for (int off = 1; off < 256; off <<= 1) {
        int x = (t >= off && t < 256) ? sd[t - off] : 0;
        __syncthreads();
        if (t < 256) sd[t] += x;
        __syncthreads();
    }
    if (t < 256) {
        int pos0 = b * CAP + sd[t] - d;
        nb0[t] = pos0;
        int node = b * 256 + t;
        if (node < N_NODES) {
            rp[node] = pos0;
            rpe[node] = pos0 + d;
            dinv[node] = rsqrtf((float)d + 1.0f);
            atomicAdd(&cnt[batch[node]], 1);
        }
    }
    __syncthreads();
#pragma unroll
    for (int g = 0; g < 3; g++) {
        int i0 = 4 * (t + g * 1024);
        if (i0 < n) {
#pragma unroll
            for (int k = 0; k < 4; k++) {
                if (i0 + k < n) {
                    unsigned p = pv[g][k];
                    csr[nb0[p >> 17] + rk[g][k]] = (int)(p & 0x1FFFFu);
                }
            }
        }
    }
}

// ---------- H1s = bf16( (x @ W1) * dinv[row] )  ([100000,128] @ [128,32]) ----------
__global__ void k_gemm1(const float* __restrict__ x, const float* __restrict__ W1,
                        const float* __restrict__ dinv, __hip_bfloat16* __restrict__ H1s) {
    __shared__ float Ws[128 * 32];
    __shared__ float xs[32 * 128];
    int t = threadIdx.x;
    const float4* W4 = (const float4*)W1;
    float4* Ws4 = (float4*)Ws;
#pragma unroll
    for (int i = 0; i < 4; i++) Ws4[t + 256 * i] = W4[t + 256 * i];
    int row0 = blockIdx.x * 32;
    const float4* x4 = (const float4*)(x + (size_t)row0 * 128);
    float4* xs4 = (float4*)xs;
#pragma unroll
    for (int i = 0; i < 4; i++) xs4[t + 256 * i] = x4[t + 256 * i];
    __syncthreads();
    int col = t & 31;
    int rb = (t >> 5) * 4;
    float a0 = 0.f, a1 = 0.f, a2 = 0.f, a3 = 0.f;
#pragma unroll 8
    for (int k = 0; k < 128; k++) {
        float w = Ws[k * 32 + col];
        a0 += xs[(rb + 0) * 128 + k] * w;
        a1 += xs[(rb + 1) * 128 + k] * w;
        a2 += xs[(rb + 2) * 128 + k] * w;
        a3 += xs[(rb + 3) * 128 + k] * w;
    }
    int r = row0 + rb;
    __hip_bfloat16* o = H1s + (size_t)r * 32 + col;
    o[0]  = __float2bfloat16(a0 * dinv[r + 0]);
    o[32] = __float2bfloat16(a1 * dinv[r + 1]);
    o[64] = __float2bfloat16(a2 * dinv[r + 2]);
    o[96] = __float2bfloat16(a3 * dinv[r + 3]);
}

// ---------- H2s = bf16( (h1 @ W2) * dinv[row] )  ([100000,32] @ [32,32]) ----------
__global__ void k_gemm2(const float* __restrict__ h1, const float* __restrict__ W2,
                        const float* __restrict__ dinv, __hip_bfloat16* __restrict__ H2s) {
    __shared__ float Ws[32 * 32];
    __shared__ float xs[32 * 32];
    int t = threadIdx.x;
    ((float4*)Ws)[t] = ((const float4*)W2)[t];
    int row0 = blockIdx.x * 32;
    ((float4*)xs)[t] = ((const float4*)(h1 + (size_t)row0 * 32))[t];
    __syncthreads();
    int col = t & 31;
    int rb = (t >> 5) * 4;
    float a0 = 0.f, a1 = 0.f, a2 = 0.f, a3 = 0.f;
#pragma unroll
    for (int k = 0; k < 32; k++) {
        float w = Ws[k * 32 + col];
        a0 += xs[(rb + 0) * 32 + k] * w;
        a1 += xs[(rb + 1) * 32 + k] * w;
        a2 += xs[(rb + 2) * 32 + k] * w;
        a3 += xs[(rb + 3) * 32 + k] * w;
    }
    int r = row0 + rb;
    __hip_bfloat16* o = H2s + (size_t)r * 32 + col;
    o[0]  = __float2bfloat16(a0 * dinv[r + 0]);
    o[32] = __float2bfloat16(a1 * dinv[r + 1]);
    o[64] = __float2bfloat16(a2 * dinv[r + 2]);
    o[96] = __float2bfloat16(a3 * dinv[r + 3]);
}

// ---------- layer-1 aggregation: one wave per dst node, 16 edges in flight ----
__global__ void k_gather1(const __hip_bfloat16* __restrict__ Hs, const float* __restrict__ dinv,
                          const int* __restrict__ rp, const int* __restrict__ rpe,
                          const int* __restrict__ csr,
                          const float* __restrict__ bias, float* __restrict__ hout) {
    int wid = (blockIdx.x * 256 + threadIdx.x) >> 6;
    if (wid >= N_NODES) return;
    const unsigned* H32 = (const unsigned*)Hs;   // row stride 16 uints
    int lane = threadIdx.x & 63;
    int f2 = lane & 15;
    int q = lane >> 4;
    int beg = rp[wid], end = rpe[wid];
    float ax = 0.f, ay = 0.f;
    int e = beg + q;
    for (; e + 12 < end; e += 16) {
        int s0 = csr[e];
        int s1 = csr[e + 4];
        int s2 = csr[e + 8];
        int s3 = csr[e + 12];
        unsigned v0 = H32[(size_t)s0 * 16 + f2];
        unsigned v1 = H32[(size_t)s1 * 16 + f2];
        unsigned v2 = H32[(size_t)s2 * 16 + f2];
        unsigned v3 = H32[(size_t)s3 * 16 + f2];
        ax += blo(v0) + blo(v1) + blo(v2) + blo(v3);
        ay += bhi(v0) + bhi(v1) + bhi(v2) + bhi(v3);
    }
    for (; e < end; e += 4) {
        unsigned v = H32[(size_t)csr[e] * 16 + f2];
        ax += blo(v); ay += bhi(v);
    }
    ax += __shfl_xor(ax, 16); ay += __shfl_xor(ay, 16);
    ax += __shfl_xor(ax, 32); ay += __shfl_xor(ay, 32);
    if (q == 0) {
        float di = dinv[wid];
        unsigned vw = H32[(size_t)wid * 16 + f2];
        float2 bb = *(const float2*)(bias + f2 * 2);
        float2 o;
        o.x = fmaxf((ax + blo(vw)) * di + bb.x, 0.f);
        o.y = fmaxf((ay + bhi(vw)) * di + bb.y, 0.f);
        *(float2*)(hout + (size_t)wid * 32 + f2 * 2) = o;
    }
}

// ---------- layer-2 aggregation fused with mean-pool numerator ----------
__global__ void k_gather2(const __hip_bfloat16* __restrict__ Hs, const float* __restrict__ dinv,
                          const int* __restrict__ rp, const int* __restrict__ rpe,
                          const int* __restrict__ csr,
                          const float* __restrict__ bias, const int* __restrict__ batch,
                          float* __restrict__ pool) {
    int wid = (blockIdx.x * 256 + threadIdx.x) >> 6;
    if (wid >= N_NODES) return;
    const unsigned* H32 = (const unsigned*)Hs;
    int lane = threadIdx.x & 63;
    int f2 = lane & 15;
    int q = lane >> 4;
    int beg = rp[wid], end = rpe[wid];
    float ax = 0.f, ay = 0.f;
    int e = beg + q;
    for (; e + 12 < end; e += 16) {
        int s0 = csr[e];
        int s1 = csr[e + 4];
        int s2 = csr[e + 8];
        int s3 = csr[e + 12];
        unsigned v0 = H32[(size_t)s0 * 16 + f2];
        unsigned v1 = H32[(size_t)s1 * 16 + f2];
        unsigned v2 = H32[(size_t)s2 * 16 + f2];
        unsigned v3 = H32[(size_t)s3 * 16 + f2];
        ax += blo(v0) + blo(v1) + blo(v2) + blo(v3);
        ay += bhi(v0) + bhi(v1) + bhi(v2) + bhi(v3);
    }
    for (; e < end; e += 4) {
        unsigned v = H32[(size_t)csr[e] * 16 + f2];
        ax += blo(v); ay += bhi(v);
    }
    ax += __shfl_xor(ax, 16); ay += __shfl_xor(ay, 16);
    ax += __shfl_xor(ax, 32); ay += __shfl_xor(ay, 32);
    if (q == 0) {
        float di = dinv[wid];
        unsigned vw = H32[(size_t)wid * 16 + f2];
        float2 bb = *(const float2*)(bias + f2 * 2);
        float vx = fmaxf((ax + blo(vw)) * di + bb.x, 0.f);
        float vy = fmaxf((ay + bhi(vw)) * di + bb.y, 0.f);
        int g = batch[wid];
        atomicAdd(&pool[(size_t)g * 32 + f2 * 2 + 0], vx);
        atomicAdd(&pool[(size_t)g * 32 + f2 * 2 + 1], vy);
    }
}

// ---------- head ----------
__global__ void k_final(const float* __restrict__ pool, const int* __restrict__ cnt,
                        const float* __restrict__ Wl, const float* __restrict__ bl,
                        float* __restrict__ out) {
    int g = blockIdx.x * 256 + threadIdx.x;
    if (g >= N_GRAPHS) return;
    float inv = 1.0f / fmaxf((float)cnt[g], 1.0f);
    float a0 = bl[0], a1 = bl[1];
#pragma unroll
    for (int f = 0; f < 32; f++) {
        float p = pool[g * 32 + f] * inv;
        a0 += p * Wl[f * 2 + 0];
        a1 += p * Wl[f * 2 + 1];
    }
    out[g * 2 + 0] = a0;
    out[g * 2 + 1] = a1;
}

extern "C" void kernel_launch(void* const* d_in, const int* in_sizes, int n_in,
                              void* d_out, int out_size, void* d_ws, size_t ws_size,
                              hipStream_t stream) {
    const float* x    = (const float*)d_in[0];
    const int*   ei   = (const int*)d_in[1];
    const int*   batch= (const int*)d_in[2];
    const float* W1   = (const float*)d_in[3];
    const float* b1   = (const float*)d_in[4];
    const float* W2   = (const float*)d_in[5];
    const float* b2   = (const float*)d_in[6];
    const float* Wl   = (const float*)d_in[7];
    const float* bl   = (const float*)d_in[8];
    float* out = (float*)d_out;

    char* w = (char*)d_ws;
    size_t off = 0;
    auto take = [&](size_t bytes) -> char* {
        char* p = w + off;
        off = (off + bytes + 255) & ~(size_t)255;
        return p;
    };
    __hip_bfloat16* H1s = (__hip_bfloat16*)take((size_t)N_NODES * 32 * 2);
    float*          h1  = (float*)take((size_t)N_NODES * 32 * 4);
    // packed (NBUK*CAP*4B = 16 MB) and H2s (6.4 MB) alias: disjoint lifetimes
    // (packed dies at k_csr; H2s born at k_gemm2).
    char*           shared = take((size_t)NBUK * CAP * 4);
    unsigned*       packed = (unsigned*)shared;
    __hip_bfloat16* H2s    = (__hip_bfloat16*)shared;
    int*      csr    = (int*)  take((size_t)NBUK * CAP * 4);
    float*    dinv   = (float*)take((size_t)N_NODES * 4);
    int*      rp     = (int*)  take((size_t)N_NODES * 4);
    int*      rpe    = (int*)  take((size_t)N_NODES * 4);
    int*      gcnt   = (int*)  take((size_t)NBUK * 4);
    float*    pool   = (float*)take((size_t)N_GRAPHS * 32 * 4);
    int*      cnt    = (int*)  take((size_t)N_GRAPHS * 4);

    hipMemsetAsync(gcnt, 0, (size_t)NBUK * 4, stream);
    hipMemsetAsync(pool, 0, (size_t)N_GRAPHS * 32 * 4, stream);
    hipMemsetAsync(cnt, 0, (size_t)N_GRAPHS * 4, stream);

    k_binfill<<<FILL_BLOCKS, 1024, 0, stream>>>(ei, gcnt, packed);
    k_csr    <<<NBUK, 1024, 0, stream>>>(packed, gcnt, batch, rp, rpe, dinv, csr, cnt);
    k_gemm1  <<<N_NODES / 32, 256, 0, stream>>>(x, W1, dinv, H1s);
    k_gather1<<<N_NODES / 4, 256, 0, stream>>>(H1s, dinv, rp, rpe, csr, b1, h1);
    k_gemm2  <<<N_NODES / 32, 256, 0, stream>>>(h1, W2, dinv, H2s);
    k_gather2<<<N_NODES / 4, 256, 0, stream>>>(H2s, dinv, rp, rpe, csr, b2, batch, pool);
    k_final  <<<2, 256, 0, stream>>>(pool, cnt, Wl, bl, out);
}